// Round 1
// baseline (1872.408 us; speedup 1.0000x reference)
//
#include <hip/hip_runtime.h>

#define HDIM 64
#define TSTEPS 5
#define BLOCK 64

__device__ __forceinline__ float sigmoidf_(float v) {
    return 1.0f / (1.0f + __expf(-v));
}
__device__ __forceinline__ float tanh_(float v) {
    // 1 - 2/(e^{2v}+1); stable for |v| <= ~40 given bounded gates/cell here
    return 1.0f - 2.0f / (__expf(2.0f * v) + 1.0f);
}

__global__ __launch_bounds__(BLOCK) void lstm_fused_kernel(
    const float* __restrict__ x,      // [B, T, 1]
    const float* __restrict__ W_ih,   // [4H, 1] -> [256]
    const float* __restrict__ W_hh,   // [4H, H] row-major
    const float* __restrict__ b_ih,   // [4H]
    const float* __restrict__ b_hh,   // [4H]
    const float* __restrict__ W_fc,   // [1, H] -> [64]
    const float* __restrict__ b_fc,   // [1]
    float* __restrict__ out,          // [B, 1]
    int B)
{
    // Per-thread c and h_new need dynamic indexing (rolled j-loop) -> LDS.
    // Layout [j][tid]: lane-consecutive addresses -> 2 lanes/bank, conflict-free.
    __shared__ float c_s[HDIM * BLOCK];
    __shared__ float hn_s[HDIM * BLOCK];

    const int tid = threadIdx.x;
    const int b   = blockIdx.x * BLOCK + tid;
    if (b >= B) return;

    const float* __restrict__ xb = x + (long)b * TSTEPS;

    float h[HDIM];   // old hidden state, registers, static indexing only

    // ---- t = 0 peeled: h = c = 0, so gates are input contribution only ----
    {
        const float xt = xb[0];
        #pragma unroll 1
        for (int j = 0; j < HDIM; j++) {
            float gi = fmaf(xt, W_ih[0 * HDIM + j], b_ih[0 * HDIM + j] + b_hh[0 * HDIM + j]);
            float gg = fmaf(xt, W_ih[2 * HDIM + j], b_ih[2 * HDIM + j] + b_hh[2 * HDIM + j]);
            float go = fmaf(xt, W_ih[3 * HDIM + j], b_ih[3 * HDIM + j] + b_hh[3 * HDIM + j]);
            float c  = sigmoidf_(gi) * tanh_(gg);      // f*c0 = 0
            c_s[j * BLOCK + tid]  = c;
            hn_s[j * BLOCK + tid] = sigmoidf_(go) * tanh_(c);
        }
        #pragma unroll
        for (int j = 0; j < HDIM; j++) h[j] = hn_s[j * BLOCK + tid];
    }

    // ---- t = 1 .. T-1 ----
    #pragma unroll 1
    for (int t = 1; t < TSTEPS; t++) {
        const float xt = xb[t];
        #pragma unroll 1
        for (int j = 0; j < HDIM; j++) {
            float gi = fmaf(xt, W_ih[0 * HDIM + j], b_ih[0 * HDIM + j] + b_hh[0 * HDIM + j]);
            float gf = fmaf(xt, W_ih[1 * HDIM + j], b_ih[1 * HDIM + j] + b_hh[1 * HDIM + j]);
            float gg = fmaf(xt, W_ih[2 * HDIM + j], b_ih[2 * HDIM + j] + b_hh[2 * HDIM + j]);
            float go = fmaf(xt, W_ih[3 * HDIM + j], b_ih[3 * HDIM + j] + b_hh[3 * HDIM + j]);

            // Uniform addresses (j is a uniform loop index) -> scalar loads,
            // broadcast SGPR operand into v_fmac.
            const float* __restrict__ wi = W_hh + (0 * HDIM + j) * HDIM;
            const float* __restrict__ wf = W_hh + (1 * HDIM + j) * HDIM;
            const float* __restrict__ wg = W_hh + (2 * HDIM + j) * HDIM;
            const float* __restrict__ wo = W_hh + (3 * HDIM + j) * HDIM;

            #pragma unroll
            for (int k = 0; k < HDIM; k++) {
                const float hk = h[k];
                gi = fmaf(hk, wi[k], gi);
                gf = fmaf(hk, wf[k], gf);
                gg = fmaf(hk, wg[k], gg);
                go = fmaf(hk, wo[k], go);
            }

            const float c_old = c_s[j * BLOCK + tid];
            const float c     = sigmoidf_(gf) * c_old + sigmoidf_(gi) * tanh_(gg);
            c_s[j * BLOCK + tid]  = c;
            hn_s[j * BLOCK + tid] = sigmoidf_(go) * tanh_(c);
        }
        #pragma unroll
        for (int j = 0; j < HDIM; j++) h[j] = hn_s[j * BLOCK + tid];
    }

    // ---- final FC: out[b] = h . W_fc + b_fc ----
    float acc = b_fc[0];
    #pragma unroll
    for (int j = 0; j < HDIM; j++) acc = fmaf(h[j], W_fc[j], acc);
    out[b] = acc;
}

extern "C" void kernel_launch(void* const* d_in, const int* in_sizes, int n_in,
                              void* d_out, int out_size, void* d_ws, size_t ws_size,
                              hipStream_t stream) {
    const float* x    = (const float*)d_in[0];
    const float* W_ih = (const float*)d_in[1];
    const float* W_hh = (const float*)d_in[2];
    const float* b_ih = (const float*)d_in[3];
    const float* b_hh = (const float*)d_in[4];
    const float* W_fc = (const float*)d_in[5];
    const float* b_fc = (const float*)d_in[6];
    float* out = (float*)d_out;

    const int B = in_sizes[0] / TSTEPS;   // x is [B, T, 1]
    const int grid = (B + BLOCK - 1) / BLOCK;
    lstm_fused_kernel<<<grid, BLOCK, 0, stream>>>(x, W_ih, W_hh, b_ih, b_hh,
                                                  W_fc, b_fc, out, B);
}

// Round 2
// 929.500 us; speedup vs baseline: 2.0144x; 2.0144x over previous
//
#include <hip/hip_runtime.h>

#define HDIM 64
#define TSTEPS 5
#define EPB 64          // batch elements per block
#define BLOCK 256       // 4 waves; wave s handles j in [s*16, s*16+16)

__device__ __forceinline__ float sigmoidf_(float v) {
    return 1.0f / (1.0f + __expf(-v));
}
__device__ __forceinline__ float tanhf_(float v) {
    return 1.0f - 2.0f / (__expf(2.0f * v) + 1.0f);
}

__global__ __launch_bounds__(BLOCK) void lstm_fused_kernel(
    const float* __restrict__ x,      // [B, T, 1]
    const float* __restrict__ W_ih,   // [4H, 1]
    const float* __restrict__ W_hh,   // [4H, H] row-major
    const float* __restrict__ b_ih,   // [4H]
    const float* __restrict__ b_hh,   // [4H]
    const float* __restrict__ W_fc,   // [1, H]
    const float* __restrict__ b_fc,   // [1]
    float* __restrict__ out,          // [B, 1]
    int B)
{
    __shared__ float h_s[HDIM * EPB];   // 16 KB, [k][e] lane-consecutive
    __shared__ float part_s[4 * EPB];   // 1 KB, FC partials

    const int tid = threadIdx.x;
    const int e   = tid & 63;                                   // batch lane
    const int s   = __builtin_amdgcn_readfirstlane(tid >> 6);   // wave id, FORCED uniform
    const int b   = blockIdx.x * EPB + e;
    const int bc  = b < B ? b : (B - 1);                        // clamp (tail safety)

    const float* __restrict__ xb = x + (long)bc * TSTEPS;
    const int jbase = s * 16;

    float c[16], hn[16];

    // ---- t = 0 peeled: h = c = 0 ----
    {
        const float xt = xb[0];
        #pragma unroll
        for (int jj = 0; jj < 16; jj++) {
            const int j = jbase + jj;
            float gi = fmaf(xt, W_ih[0 * HDIM + j], b_ih[0 * HDIM + j] + b_hh[0 * HDIM + j]);
            float gg = fmaf(xt, W_ih[2 * HDIM + j], b_ih[2 * HDIM + j] + b_hh[2 * HDIM + j]);
            float go = fmaf(xt, W_ih[3 * HDIM + j], b_ih[3 * HDIM + j] + b_hh[3 * HDIM + j]);
            c[jj]  = sigmoidf_(gi) * tanhf_(gg);
            hn[jj] = sigmoidf_(go) * tanhf_(c[jj]);
            h_s[j * EPB + e] = hn[jj];
        }
    }
    __syncthreads();

    // ---- t = 1 .. T-1 ----
    #pragma unroll 1
    for (int t = 1; t < TSTEPS; t++) {
        const float xt = xb[t];

        // 4 sub-chunks of 4 j's: 16 accumulators live at a time
        #pragma unroll
        for (int q4 = 0; q4 < 4; q4++) {
            const int jb = jbase + q4 * 4;    // rows g*64 + jb + q, all wave-uniform
            float ai[4], af[4], ag[4], ao[4];
            #pragma unroll
            for (int q = 0; q < 4; q++) {
                const int j = jb + q;
                ai[q] = fmaf(xt, W_ih[0 * HDIM + j], b_ih[0 * HDIM + j] + b_hh[0 * HDIM + j]);
                af[q] = fmaf(xt, W_ih[1 * HDIM + j], b_ih[1 * HDIM + j] + b_hh[1 * HDIM + j]);
                ag[q] = fmaf(xt, W_ih[2 * HDIM + j], b_ih[2 * HDIM + j] + b_hh[2 * HDIM + j]);
                ao[q] = fmaf(xt, W_ih[3 * HDIM + j], b_ih[3 * HDIM + j] + b_hh[3 * HDIM + j]);
            }

            #pragma unroll
            for (int k = 0; k < HDIM; k++) {
                const float hk = h_s[k * EPB + e];   // lane-consecutive -> conflict-free
                #pragma unroll
                for (int q = 0; q < 4; q++) {
                    ai[q] = fmaf(hk, W_hh[(0 * HDIM + jb + q) * HDIM + k], ai[q]);
                    af[q] = fmaf(hk, W_hh[(1 * HDIM + jb + q) * HDIM + k], af[q]);
                    ag[q] = fmaf(hk, W_hh[(2 * HDIM + jb + q) * HDIM + k], ag[q]);
                    ao[q] = fmaf(hk, W_hh[(3 * HDIM + jb + q) * HDIM + k], ao[q]);
                }
            }

            #pragma unroll
            for (int q = 0; q < 4; q++) {
                const int jj = q4 * 4 + q;
                const float cn = sigmoidf_(af[q]) * c[jj] + sigmoidf_(ai[q]) * tanhf_(ag[q]);
                c[jj]  = cn;
                hn[jj] = sigmoidf_(ao[q]) * tanhf_(cn);
            }
        }

        __syncthreads();   // all h_s reads for this timestep complete
        #pragma unroll
        for (int jj = 0; jj < 16; jj++) h_s[(jbase + jj) * EPB + e] = hn[jj];
        __syncthreads();   // new h visible to all waves
    }

    // ---- FC: per-wave partial dot over its 16 j's, reduce via LDS ----
    float p = 0.0f;
    #pragma unroll
    for (int jj = 0; jj < 16; jj++) p = fmaf(hn[jj], W_fc[jbase + jj], p);
    part_s[s * EPB + e] = p;
    __syncthreads();

    if (s == 0 && b < B) {
        out[b] = part_s[e] + part_s[EPB + e] + part_s[2 * EPB + e] + part_s[3 * EPB + e]
               + b_fc[0];
    }
}

extern "C" void kernel_launch(void* const* d_in, const int* in_sizes, int n_in,
                              void* d_out, int out_size, void* d_ws, size_t ws_size,
                              hipStream_t stream) {
    const float* x    = (const float*)d_in[0];
    const float* W_ih = (const float*)d_in[1];
    const float* W_hh = (const float*)d_in[2];
    const float* b_ih = (const float*)d_in[3];
    const float* b_hh = (const float*)d_in[4];
    const float* W_fc = (const float*)d_in[5];
    const float* b_fc = (const float*)d_in[6];
    float* out = (float*)d_out;

    const int B = in_sizes[0] / TSTEPS;   // x is [B, T, 1]
    const int grid = (B + EPB - 1) / EPB;
    lstm_fused_kernel<<<grid, BLOCK, 0, stream>>>(x, W_ih, W_hh, b_ih, b_hh,
                                                  W_fc, b_fc, out, B);
}

// Round 3
// 262.808 us; speedup vs baseline: 7.1246x; 3.5368x over previous
//
#include <hip/hip_runtime.h>

#define HDIM   64
#define TSTEPS 5
#define WAVES  8
#define BLOCK  (WAVES * 64)
#define EPW    16               // batch per wave = MFMA M
#define EPB    (WAVES * EPW)    // 128 batch per block

typedef _Float16 f16x8 __attribute__((ext_vector_type(8)));
typedef float    f32x4 __attribute__((ext_vector_type(4)));

__device__ __forceinline__ float sigmoidf_(float v) {
    return 1.0f / (1.0f + __expf(-v));
}
__device__ __forceinline__ float tanhf_(float v) {
    return 1.0f - 2.0f / (__expf(2.0f * v) + 1.0f);
}

// Gates as D[m=batch e][n=gate row j'] = sum_k A[e][k=hidden] * B[k][j'] (+bias terms)
// A = h^T (per-timestep, rebuilt), B = W_hh^T (staged once).
// 16x16x32 f16 layouts (verified, dtype-independent):
//   A-frag: lane holds A[m=lane&15][k = kh*32 + (lane>>4)*8 + i], i=0..7
//   B-frag: lane holds B[k = kh*32 + (lane>>4)*8 + i][n = ntile*16 + (lane&15)]
//   C/D:    lane holds D[m = (lane>>4)*4 + reg][n = ntile*16 + (lane&15)]
__global__ __launch_bounds__(BLOCK, 4) void lstm_mfma_kernel(
    const float* __restrict__ x,      // [B, T, 1]
    const float* __restrict__ W_ih,   // [256, 1]
    const float* __restrict__ W_hh,   // [256, 64]
    const float* __restrict__ b_ih,   // [256]
    const float* __restrict__ b_hh,   // [256]
    const float* __restrict__ W_fc,   // [1, 64]
    const float* __restrict__ b_fc,   // [1]
    float* __restrict__ out,          // [B, 1]
    int B)
{
    // W fragments, fragment-linear: slot s = (ntile*2 + kh)*64 + lane, 8 fp16 each.
    __shared__ _Float16 Wf[2048 * 8];          // 32 KB
    // Per-wave h fragment buffer, fragment-linear: [kh][lane][i] 8 fp16 per lane.
    __shared__ _Float16 hbuf[WAVES * 1024];    // 16 KB
    __shared__ float    wih_s[256];            // 1 KB
    __shared__ float    cb_s[256];             // 1 KB (b_ih + b_hh)

    const int tid = threadIdx.x;

    // ---- one-time staging: W_hh -> fp16 B-fragments ----
    #pragma unroll
    for (int s0 = 0; s0 < 2048; s0 += BLOCK) {
        const int s  = s0 + tid;
        const int ln = s & 63;
        const int kh = (s >> 6) & 1;
        const int n  = s >> 7;
        const int j  = n * 16 + (ln & 15);                 // gate row j'
        const int k0 = kh * 32 + ((ln >> 4) & 3) * 8;      // hidden k
        const float* src = W_hh + j * HDIM + k0;
        #pragma unroll
        for (int i = 0; i < 8; i++)
            Wf[s * 8 + i] = (_Float16)src[i];
    }
    if (tid < 256) {
        wih_s[tid] = W_ih[tid];
        cb_s[tid]  = b_ih[tid] + b_hh[tid];
    }
    __syncthreads();   // only barrier in the kernel

    const int lane = tid & 63;
    const int wave = tid >> 6;
    const int m    = lane & 15;    // C-layout column (gate-row local) / A row m
    const int q    = lane >> 4;    // quad
    const int eg0  = (blockIdx.x * WAVES + wave) * EPW;

    _Float16* hb = hbuf + wave * 1024;

    float c[16];    // cell state, [gr*4 + r] <-> (j = gr*16 + m, e = q*4 + r)
    float hv[16];   // last hidden state, same indexing

    for (int t = 0; t < TSTEPS; t++) {
        // x for this lane's 4 batch rows (same addr across the 16 m-lanes -> broadcast)
        float xt[4];
        #pragma unroll
        for (int r = 0; r < 4; r++) {
            int e = eg0 + q * 4 + r;
            if (e >= B) e = B - 1;
            xt[r] = x[(long)e * TSTEPS + t];
        }

        // h A-fragments from previous timestep (same-wave LDS, no barrier needed)
        f16x8 hA0, hA1;
        if (t > 0) {
            hA0 = *(const f16x8*)(hb + lane * 8);          // kh = 0
            hA1 = *(const f16x8*)(hb + 512 + lane * 8);    // kh = 1
        }

        #pragma unroll
        for (int gr = 0; gr < 4; gr++) {       // j' chunk: j = gr*16 + m
            f32x4 ag[4];                       // gate G accumulator, N-tile = G*4+gr
            #pragma unroll
            for (int G = 0; G < 4; G++) ag[G] = (f32x4){0.f, 0.f, 0.f, 0.f};

            if (t > 0) {
                #pragma unroll
                for (int G = 0; G < 4; G++) {
                    const int n = G * 4 + gr;
                    f16x8 w0 = *(const f16x8*)(Wf + (n * 2 + 0) * 512 + lane * 8);
                    f16x8 w1 = *(const f16x8*)(Wf + (n * 2 + 1) * 512 + lane * 8);
                    ag[G] = __builtin_amdgcn_mfma_f32_16x16x32_f16(hA0, w0, ag[G], 0, 0, 0);
                    ag[G] = __builtin_amdgcn_mfma_f32_16x16x32_f16(hA1, w1, ag[G], 0, 0, 0);
                }
            }

            // bias + input contribution (broadcast LDS reads, conflict-free)
            const float wih0 = wih_s[0 * 64 + gr * 16 + m], cb0 = cb_s[0 * 64 + gr * 16 + m];
            const float wih1 = wih_s[1 * 64 + gr * 16 + m], cb1 = cb_s[1 * 64 + gr * 16 + m];
            const float wih2 = wih_s[2 * 64 + gr * 16 + m], cb2 = cb_s[2 * 64 + gr * 16 + m];
            const float wih3 = wih_s[3 * 64 + gr * 16 + m], cb3 = cb_s[3 * 64 + gr * 16 + m];

            #pragma unroll
            for (int r = 0; r < 4; r++) {
                const float gi = fmaf(xt[r], wih0, ag[0][r] + cb0);
                const float gf = fmaf(xt[r], wih1, ag[1][r] + cb1);
                const float gg = fmaf(xt[r], wih2, ag[2][r] + cb2);
                const float go = fmaf(xt[r], wih3, ag[3][r] + cb3);
                const int u = gr * 4 + r;
                float cn = sigmoidf_(gi) * tanhf_(gg);
                if (t > 0) cn = fmaf(sigmoidf_(gf), c[u], cn);
                c[u] = cn;
                const float hn = sigmoidf_(go) * tanhf_(cn);
                hv[u] = hn;
                if (t < TSTEPS - 1) {
                    // scatter h (fp16) into next timestep's A-fragment slots:
                    // k = j = gr*16+m -> kh = gr>>1, frag-lane = e + 16*(2*(gr&1)+(m>>3)), i = m&7
                    const int lp = (q * 4 + r) + 16 * (2 * (gr & 1) + (m >> 3));
                    hb[(gr >> 1) * 512 + lp * 8 + (m & 7)] = (_Float16)hn;
                }
            }
        }
    }

    // ---- FC epilogue: out[e] = sum_j h[j][e] * W_fc[j] + b_fc ----
    float wfc[4];
    #pragma unroll
    for (int n = 0; n < 4; n++) wfc[n] = W_fc[n * 16 + m];
    const float bfc = b_fc[0];

    #pragma unroll
    for (int r = 0; r < 4; r++) {
        float p = hv[r] * wfc[0];
        p = fmaf(hv[4 + r],  wfc[1], p);
        p = fmaf(hv[8 + r],  wfc[2], p);
        p = fmaf(hv[12 + r], wfc[3], p);
        // reduce over the 16 m-lanes (j' within chunk); masks stay inside the 16-lane group
        p += __shfl_xor(p, 1, 64);
        p += __shfl_xor(p, 2, 64);
        p += __shfl_xor(p, 4, 64);
        p += __shfl_xor(p, 8, 64);
        if (m == 0) {
            const int e = eg0 + q * 4 + r;
            if (e < B) out[e] = p + bfc;
        }
    }
}

extern "C" void kernel_launch(void* const* d_in, const int* in_sizes, int n_in,
                              void* d_out, int out_size, void* d_ws, size_t ws_size,
                              hipStream_t stream) {
    const float* x    = (const float*)d_in[0];
    const float* W_ih = (const float*)d_in[1];
    const float* W_hh = (const float*)d_in[2];
    const float* b_ih = (const float*)d_in[3];
    const float* b_hh = (const float*)d_in[4];
    const float* W_fc = (const float*)d_in[5];
    const float* b_fc = (const float*)d_in[6];
    float* out = (float*)d_out;

    const int B = in_sizes[0] / TSTEPS;   // x is [B, T, 1]
    const int grid = (B + EPB - 1) / EPB;
    lstm_mfma_kernel<<<grid, BLOCK, 0, stream>>>(x, W_ih, W_hh, b_ih, b_hh,
                                                 W_fc, b_fc, out, B);
}

// Round 4
// 153.673 us; speedup vs baseline: 12.1844x; 1.7102x over previous
//
#include <hip/hip_runtime.h>

#define HDIM   64
#define TSTEPS 5
#define WAVES  8
#define BLOCK  (WAVES * 64)
#define EPW    16               // batch per wave = MFMA M
#define EPB    (WAVES * EPW)    // 128 batch per block

typedef _Float16 f16x8 __attribute__((ext_vector_type(8)));
typedef float    f32x4 __attribute__((ext_vector_type(4)));

#define L2E 1.44269504088896340736f   // log2(e)

// Native 1-ulp ops (avoid IEEE division expansion: ~7 inst + long chains each)
__device__ __forceinline__ float rcp_(float x) { return __builtin_amdgcn_rcpf(x); }
__device__ __forceinline__ float ex2_(float x) { return __builtin_amdgcn_exp2f(x); }
// sigmoid for pre-scaled argument v = x*log2(e): 1/(1+2^-v)
__device__ __forceinline__ float sigp_(float v) { return rcp_(1.0f + ex2_(-v)); }

// Gates as D[m=batch e][n=gate row j'] = A[e][k] * B[k][j'] + C(bias + x*W_ih)
// A = h^T (per-timestep, rebuilt), B = W_hh^T (staged once, PRE-SCALED by
// log2e for i/f/o columns and 2*log2e for g columns so activations use raw
// v_exp_f32 = 2^x with no multiply).
// 16x16x32 f16 layouts (verified in R3, absmax 9.8e-4):
//   A-frag: lane holds A[m=lane&15][k = kh*32 + (lane>>4)*8 + i], i=0..7
//   B-frag: lane holds B[k = kh*32 + (lane>>4)*8 + i][n = ntile*16 + (lane&15)]
//   C/D:    lane holds D[m = (lane>>4)*4 + reg][n = ntile*16 + (lane&15)]
__global__ __launch_bounds__(BLOCK, 4) void lstm_mfma_kernel(
    const float* __restrict__ x,      // [B, T, 1]
    const float* __restrict__ W_ih,   // [256, 1]
    const float* __restrict__ W_hh,   // [256, 64]
    const float* __restrict__ b_ih,   // [256]
    const float* __restrict__ b_hh,   // [256]
    const float* __restrict__ W_fc,   // [1, 64]
    const float* __restrict__ b_fc,   // [1]
    float* __restrict__ out,          // [B, 1]
    int B)
{
    __shared__ _Float16 Wf[2048 * 8];          // 32 KB, B-fragments, fragment-linear
    __shared__ _Float16 hbuf[WAVES * 1024];    // 16 KB, per-wave h A-fragments
    __shared__ float    wih_s[256];            // 1 KB (pre-scaled)
    __shared__ float    cb_s[256];             // 1 KB (pre-scaled b_ih + b_hh)

    const int tid = threadIdx.x;

    // ---- one-time staging: W_hh -> fp16 B-fragments, log2e pre-scaled ----
    #pragma unroll
    for (int s0 = 0; s0 < 2048; s0 += BLOCK) {
        const int s  = s0 + tid;
        const int ln = s & 63;
        const int kh = (s >> 6) & 1;
        const int n  = s >> 7;                             // N-tile 0..15, gate G = n>>2
        const float scl = ((n >> 2) == 2) ? (2.0f * L2E) : L2E;
        const int j  = n * 16 + (ln & 15);                 // gate row j'
        const int k0 = kh * 32 + ((ln >> 4) & 3) * 8;      // hidden k
        const float* src = W_hh + j * HDIM + k0;
        #pragma unroll
        for (int i = 0; i < 8; i++)
            Wf[s * 8 + i] = (_Float16)(src[i] * scl);
    }
    if (tid < 256) {
        const float scl = ((tid >> 6) == 2) ? (2.0f * L2E) : L2E;
        wih_s[tid] = W_ih[tid] * scl;
        cb_s[tid]  = (b_ih[tid] + b_hh[tid]) * scl;
    }
    __syncthreads();   // only barrier in the kernel

    const int lane = tid & 63;
    const int wave = tid >> 6;
    const int m    = lane & 15;    // C-layout column (gate-row local) / A row m
    const int q    = lane >> 4;    // quad
    const int eg0  = (blockIdx.x * WAVES + wave) * EPW;

    _Float16* hb = hbuf + wave * 1024;

    // x base pointers for this lane's 4 batch rows (hoisted; per-t load is imm offset)
    const float* xp[4];
    #pragma unroll
    for (int r = 0; r < 4; r++) {
        int e = eg0 + q * 4 + r;
        if (e >= B) e = B - 1;
        xp[r] = x + (long)e * TSTEPS;
    }

    float c[16];    // cell state, SCALED by 2*log2e; [gr*4+r] <-> (j=gr*16+m, e=q*4+r)
    float hv[16];   // last hidden state (unscaled), same indexing

    for (int t = 0; t < TSTEPS; t++) {
        float xt[4];
        #pragma unroll
        for (int r = 0; r < 4; r++) xt[r] = xp[r][t];

        // h A-fragments from previous timestep (same-wave LDS, no barrier needed)
        f16x8 hA0, hA1;
        if (t > 0) {
            hA0 = *(const f16x8*)(hb + lane * 8);          // kh = 0
            hA1 = *(const f16x8*)(hb + 512 + lane * 8);    // kh = 1
        }

        #pragma unroll
        for (int gr = 0; gr < 4; gr++) {       // j' chunk: j = gr*16 + m
            // C-init: bias + x*W_ih directly as the MFMA C operand
            float wihv[4], cbv[4];
            #pragma unroll
            for (int G = 0; G < 4; G++) {
                wihv[G] = wih_s[G * 64 + gr * 16 + m];   // broadcast, conflict-free
                cbv[G]  = cb_s[G * 64 + gr * 16 + m];
            }
            f32x4 ag[4];
            #pragma unroll
            for (int G = 0; G < 4; G++)
                #pragma unroll
                for (int r = 0; r < 4; r++)
                    ag[G][r] = fmaf(xt[r], wihv[G], cbv[G]);

            if (t > 0) {
                #pragma unroll
                for (int G = 0; G < 4; G++) {
                    const int n = G * 4 + gr;
                    f16x8 w0 = *(const f16x8*)(Wf + (n * 2 + 0) * 512 + lane * 8);
                    f16x8 w1 = *(const f16x8*)(Wf + (n * 2 + 1) * 512 + lane * 8);
                    ag[G] = __builtin_amdgcn_mfma_f32_16x16x32_f16(hA0, w0, ag[G], 0, 0, 0);
                    ag[G] = __builtin_amdgcn_mfma_f32_16x16x32_f16(hA1, w1, ag[G], 0, 0, 0);
                }
            }

            #pragma unroll
            for (int r = 0; r < 4; r++) {
                const int u = gr * 4 + r;
                const float si = sigp_(ag[0][r]);
                const float sf = sigp_(ag[1][r]);
                const float so = sigp_(ag[3][r]);
                // tanh(g), output pre-scaled by 2*log2e (folds the c->exp2 scale)
                const float rg  = rcp_(ex2_(ag[2][r]) + 1.0f);
                const float tgs = fmaf(rg, -4.0f * L2E, 2.0f * L2E);
                float cs = si * tgs;
                if (t > 0) cs = fmaf(sf, c[u], cs);
                c[u] = cs;                                    // scaled domain
                const float rc = rcp_(ex2_(cs) + 1.0f);       // tanh(c) = 1-2*rc
                const float hn = so * fmaf(rc, -2.0f, 1.0f);
                hv[u] = hn;
                if (t < TSTEPS - 1) {
                    // scatter h (fp16) into next timestep's A-fragment slots
                    const int lp = (q * 4 + r) + 16 * (2 * (gr & 1) + (m >> 3));
                    hb[(gr >> 1) * 512 + lp * 8 + (m & 7)] = (_Float16)hn;
                }
            }
        }
    }

    // ---- FC epilogue: out[e] = sum_j h[j][e] * W_fc[j] + b_fc ----
    float wfc[4];
    #pragma unroll
    for (int n = 0; n < 4; n++) wfc[n] = W_fc[n * 16 + m];
    const float bfc = b_fc[0];

    #pragma unroll
    for (int r = 0; r < 4; r++) {
        float p = hv[r] * wfc[0];
        p = fmaf(hv[4 + r],  wfc[1], p);
        p = fmaf(hv[8 + r],  wfc[2], p);
        p = fmaf(hv[12 + r], wfc[3], p);
        p += __shfl_xor(p, 1, 64);
        p += __shfl_xor(p, 2, 64);
        p += __shfl_xor(p, 4, 64);
        p += __shfl_xor(p, 8, 64);
        if (m == 0) {
            const int e = eg0 + q * 4 + r;
            if (e < B) out[e] = p + bfc;
        }
    }
}

extern "C" void kernel_launch(void* const* d_in, const int* in_sizes, int n_in,
                              void* d_out, int out_size, void* d_ws, size_t ws_size,
                              hipStream_t stream) {
    const float* x    = (const float*)d_in[0];
    const float* W_ih = (const float*)d_in[1];
    const float* W_hh = (const float*)d_in[2];
    const float* b_ih = (const float*)d_in[3];
    const float* b_hh = (const float*)d_in[4];
    const float* W_fc = (const float*)d_in[5];
    const float* b_fc = (const float*)d_in[6];
    float* out = (float*)d_out;

    const int B = in_sizes[0] / TSTEPS;   // x is [B, T, 1]
    const int grid = (B + EPB - 1) / EPB;
    lstm_mfma_kernel<<<grid, BLOCK, 0, stream>>>(x, W_ih, W_hh, b_ih, b_hh,
                                                 W_fc, b_fc, out, B);
}